// Round 11
// baseline (341.190 us; speedup 1.0000x reference)
//
#include <hip/hip_runtime.h>
#include <hip/hip_bf16.h>
#include <math.h>

typedef __bf16 bf16;
typedef float f32x4 __attribute__((ext_vector_type(4)));
typedef float f32x16 __attribute__((ext_vector_type(16)));
typedef bf16 bf16x8 __attribute__((ext_vector_type(8)));
typedef bf16 bf16x4 __attribute__((ext_vector_type(4)));
typedef unsigned int uint;
typedef uint uintx2 __attribute__((ext_vector_type(2)));

#define MFMA16(a, b, c) __builtin_amdgcn_mfma_f32_16x16x32_bf16(a, b, c, 0, 0, 0)
#define MFMA32(a, b, c) __builtin_amdgcn_mfma_f32_32x32x16_bf16(a, b, c, 0, 0, 0)

static constexpr int T_SEQ = 2048;
static constexpr int CDIM  = 1024;
static constexpr int NH    = 16;
static constexpr int DH    = 64;
static constexpr float FREQ_C = 0.20762050593045998f;   // log2(10000)/64
// 1/sqrt(64) * log2(e): folded into Q so flash uses bare exp2
static constexpr float Q_SCALE = 0.18033688011112042f;

// raw v_exp_f32 (1 trans op; no denormal-fixup expansion). Safe here: all
// results are normal-range, flush-to-zero unobservable after bf16 cast.
__device__ __forceinline__ float fexp2(float x) {
    return __builtin_amdgcn_exp2f(x);
}

// pack two f32 -> bf16x2 word via scalar casts; compiler fuses to the packed
// cvt with CORRECT operand order. (r11's hand-asm cvt_pk had a different
// packing convention -> pair scramble. Do not hand-write it.)
__device__ __forceinline__ uint pack_bf16(float lo, float hi) {
    union { bf16 h[2]; uint u; } cv;
    cv.h[0] = (bf16)lo;
    cv.h[1] = (bf16)hi;
    return cv.u;
}

// async global->LDS, 16B per lane. LDS dest is wave-uniform base + lane*16.
__device__ __forceinline__ void gld_lds16(const bf16* g, bf16* l) {
    __builtin_amdgcn_global_load_lds(
        (const __attribute__((address_space(1))) void*)g,
        (__attribute__((address_space(3))) void*)l, 16, 0, 0);
}

// Accurate fast sincos: 2-term Cody-Waite reduction to [-pi,pi], then native.
__device__ __forceinline__ void fast_sincos(float x, float* s, float* c) {
    const float INV2PI = 0.15915494309189535f;
    const float PI2_HI = 6.28125f;
    const float PI2_LO = 1.9353071795864769e-3f;
    const float n = rintf(x * INV2PI);
    float r = fmaf(-n, PI2_HI, x);
    r = fmaf(-n, PI2_LO, r);
    *s = __sinf(r);
    *c = __cosf(r);
}

// ---------------------------------------------------------------------------
// RoPE cos/sin table: tab[t][p] = (cos, sin) of t * theta^(-2p/64), p=d>>1.
// ---------------------------------------------------------------------------
__global__ __launch_bounds__(256)
void rope_table(float2* __restrict__ tab) {
    const int i = blockIdx.x * 256 + threadIdx.x;   // 2048*32 entries
    const int t = i >> 5, p = i & 31;
    const float ang = (float)t * exp2f(-2.0f * (float)p * FREQ_C);
    float s, c;
    fast_sincos(ang, &s, &c);
    tab[i] = make_float2(c, s);
}

// ---------------------------------------------------------------------------
// fp32 -> bf16 conversion
// ---------------------------------------------------------------------------
__global__ __launch_bounds__(256)
void cvt_f32_bf16(const float* __restrict__ in, bf16* __restrict__ out, int n8) {
    const int i = blockIdx.x * 256 + threadIdx.x;
    if (i >= n8) return;
    const f32x4* p = (const f32x4*)(in + (size_t)i * 8);
    const f32x4 lo = p[0], hi = p[1];
    bf16x8 o;
    o[0] = (bf16)lo[0]; o[1] = (bf16)lo[1]; o[2] = (bf16)lo[2]; o[3] = (bf16)lo[3];
    o[4] = (bf16)hi[0]; o[5] = (bf16)hi[1]; o[6] = (bf16)hi[2]; o[7] = (bf16)hi[3];
    *(bf16x8*)(out + (size_t)i * 8) = o;
}

// ---------------------------------------------------------------------------
// 128x128 GEMM core, BK=64, 2-barrier (r12-proven). Used by gemm_proj.
// Five schedule variants (2-bar / dbuf / reads-first / dual-M / counted
// vmcnt) all measured 117us on qkv -> the drain is NOT the cost; this is
// the structure's floor. Keep the simplest correct form.
// ---------------------------------------------------------------------------
#define GEMM_CORE(Abase, Bbase, KDIM)                                            \
    f32x4 acc[4][4] = {};                                                        \
    for (int kk = 0; kk < (KDIM); kk += 64) {                                    \
        __syncthreads();                                                         \
        _Pragma("unroll")                                                        \
        for (int u = 0; u < 4; u++) {                                            \
            const int st = wave * 4 + u, mg = st >> 1, kg = st & 1;              \
            gld_lds16(Abase + (size_t)(mg * 16 + sm) * (KDIM) + kk + kg * 32 + sc * 8, \
                      &ash[st * 512]);                                           \
            gld_lds16(Bbase + (size_t)(mg * 16 + sm) * (KDIM) + kk + kg * 32 + sc * 8, \
                      &bsh[st * 512]);                                           \
        }                                                                        \
        __syncthreads();                                                         \
        _Pragma("unroll")                                                        \
        for (int kg = 0; kg < 2; kg++) {                                         \
            bf16x8 af[4], bfr[4];                                                \
            _Pragma("unroll")                                                    \
            for (int a = 0; a < 4; a++)                                          \
                af[a] = *(const bf16x8*)&ash[((wm * 4 + a) * 2 + kg) * 512 + lane * 8]; \
            _Pragma("unroll")                                                    \
            for (int b = 0; b < 4; b++)                                          \
                bfr[b] = *(const bf16x8*)&bsh[((wn * 4 + b) * 2 + kg) * 512 + lane * 8]; \
            _Pragma("unroll")                                                    \
            for (int a = 0; a < 4; a++)                                          \
                _Pragma("unroll")                                                \
                for (int b = 0; b < 4; b++)                                      \
                    acc[a][b] = MFMA16(af[a], bfr[b], acc[a][b]);                \
        }                                                                        \
    }

// ---------------------------------------------------------------------------
// QKV GEMM + fused RoPE, BK=128 variant: 8 K-steps instead of 16 — halves
// the per-step fixed costs (barrier pairs, drains, loop overhead) at the
// same LDS-traffic-per-MFMA. m132's BK=128 regression was an occupancy cliff
// (3->2 blocks/CU) that doesn't apply here: we're already at 2 blocks/CU
// and measured occupancy was identical at 32KB vs 64KB LDS.
// LDS: 32 subtiles x [16 rows x 32 cols] per operand (64KB total).
// Stage: wave covers subtiles st = wave*8+u, mg = st>>2, kg = st&3; the
// staging lane order IS the MFMA fragment order (row=lane&15,
// k=(lane>>4)*8), so ds_reads are 1KB contiguous per wave (conflict-free).
// XCD-chunked swizzle, bm-fastest (r16-verified FETCH 85->51MB).
// ---------------------------------------------------------------------------
__global__ __launch_bounds__(256)
void gemm_qkv(const bf16* __restrict__ X, const bf16* __restrict__ W,
              bf16* __restrict__ Qo, bf16* __restrict__ Ko, bf16* __restrict__ Vt,
              const float2* __restrict__ tab) {
    __shared__ __align__(16) bf16 ash[32 * 512];
    __shared__ __align__(16) bf16 bsh[32 * 512];
    const int tid = threadIdx.x, lane = tid & 63, wave = tid >> 6;
    const int quad = lane >> 4, l16 = lane & 15;
    const int wm = wave >> 1, wn = wave & 1;
    const int lin = blockIdx.y * 24 + blockIdx.x;        // 0..1535
    const int xcd = lin & 7, j = lin >> 3;               // j in [0,192)
    const int bm = xcd * 8 + (j & 7), bn = j >> 3;       // bm-fastest in chunk
    const int sm = lane & 15, sc = lane >> 4;

    const bf16* Abase = X + (size_t)(bm * 128) * CDIM;
    const bf16* Bbase = W + (size_t)(bn * 128) * CDIM;

    f32x4 acc[4][4] = {};
    for (int kk = 0; kk < CDIM; kk += 128) {
        __syncthreads();
#pragma unroll
        for (int u = 0; u < 8; u++) {
            const int st = wave * 8 + u, mg = st >> 2, kg = st & 3;
            const size_t off = (size_t)(mg * 16 + sm) * CDIM + kk + kg * 32 + sc * 8;
            gld_lds16(Abase + off, &ash[st * 512]);
            gld_lds16(Bbase + off, &bsh[st * 512]);
        }
        __syncthreads();
#pragma unroll
        for (int kg = 0; kg < 4; kg++) {
            bf16x8 af[4], bfr[4];
#pragma unroll
            for (int a = 0; a < 4; a++)
                af[a] = *(const bf16x8*)&ash[((wm * 4 + a) * 4 + kg) * 512 + lane * 8];
#pragma unroll
            for (int b = 0; b < 4; b++)
                bfr[b] = *(const bf16x8*)&bsh[((wn * 4 + b) * 4 + kg) * 512 + lane * 8];
#pragma unroll
            for (int a = 0; a < 4; a++)
#pragma unroll
                for (int b = 0; b < 4; b++)
                    acc[a][b] = MFMA16(af[a], bfr[b], acc[a][b]);
        }
    }

    const int rr    = (bn * 128) >> 10;          // 0=q 1=k 2=v (block-uniform)
    const int nsec  = (bn * 128) & 1023;
    const int batch = (bm * 128) >> 11;
    const int tb    = ((bm * 128) & 2047) + wm * 64;

    if (rr == 2) {
#pragma unroll
        for (int b = 0; b < 4; b++) {
            const int n = nsec + wn * 64 + b * 16 + l16;
            const int h = n >> 6, d = n & 63;
            bf16* vp = Vt + ((size_t)(batch * NH + h) * DH + d) * T_SEQ;
#pragma unroll
            for (int a = 0; a < 4; a++) {
                const int t0 = tb + a * 16 + quad * 4;
                bf16x4 pk4 = { (bf16)acc[a][b][0], (bf16)acc[a][b][1],
                               (bf16)acc[a][b][2], (bf16)acc[a][b][3] };
                *(bf16x4*)(vp + t0) = pk4;
            }
        }
    } else {
        bf16* Dst = (rr == 0) ? Qo : Ko;
        const float scale = (rr == 0) ? Q_SCALE : 1.0f;
#pragma unroll
        for (int b = 0; b < 4; b++) {
            const int n = nsec + wn * 64 + b * 16 + l16;
            const int h = n >> 6, d = n & 63;
            const int p = d >> 1, odd = d & 1;
            bf16* dp = Dst + (size_t)(batch * NH + h) * T_SEQ * DH + d;
#pragma unroll
            for (int a = 0; a < 4; a++) {
#pragma unroll
                for (int r = 0; r < 4; r++) {
                    const int t = tb + a * 16 + quad * 4 + r;
                    const float val = acc[a][b][r];
                    const float partner = __shfl_xor(val, 1);  // pair element d^1
                    const float2 cs = tab[t * 32 + p];
                    float o = odd ? (partner * cs.y + val * cs.x)
                                  : (val * cs.x - partner * cs.y);
                    dp[(size_t)t * DH] = (bf16)(o * scale);
                }
            }
        }
    }
}

// ---------------------------------------------------------------------------
// Out-projection GEMM, fp32 output. r12-proven core + chunked swizzle,
// bm-fastest (512 % 8 == 0).
// ---------------------------------------------------------------------------
__global__ __launch_bounds__(256)
void gemm_proj(const bf16* __restrict__ X, const bf16* __restrict__ W,
               float* __restrict__ Out) {
    __shared__ __align__(16) bf16 ash[16 * 512];
    __shared__ __align__(16) bf16 bsh[16 * 512];
    const int tid = threadIdx.x, lane = tid & 63, wave = tid >> 6;
    const int quad = lane >> 4, l16 = lane & 15;
    const int wm = wave >> 1, wn = wave & 1;
    const int lin = blockIdx.y * 8 + blockIdx.x;         // 0..511
    const int xcd = lin & 7, j = lin >> 3;               // j in [0,64)
    const int bm = xcd * 8 + (j & 7), bn = j >> 3;       // bm-fastest in chunk
    const int sm = lane & 15, sc = lane >> 4;

    const bf16* Abase = X + (size_t)(bm * 128) * CDIM;
    const bf16* Bbase = W + (size_t)(bn * 128) * CDIM;
    GEMM_CORE(Abase, Bbase, CDIM)

#pragma unroll
    for (int b = 0; b < 4; b++) {
        const int n = bn * 128 + wn * 64 + b * 16 + l16;
#pragma unroll
        for (int a = 0; a < 4; a++) {
            const int m = bm * 128 + wm * 64 + a * 16 + quad * 4;
#pragma unroll
            for (int r = 0; r < 4; r++)
                Out[(size_t)(m + r) * CDIM + n] = acc[a][b][r];
        }
    }
}

// ---------------------------------------------------------------------------
// Flash r13 + T5 s_setprio around MFMA clusters (m191: +4-7% on attn —
// flash's blocks are independent and phase-diverse on a CU, exactly the
// regime where priority arbitration pays; NOT the lockstep-GEMM regime
// where it was null). Everything else identical to the proven 322.8us r13.
// permlane32_swap convention (r10-verified):
//   ret[0] (vdst') = {vdst.lo , src0.lo}; ret[1] (src0') = {vdst.hi , src0.hi}
// ---------------------------------------------------------------------------
__global__ __launch_bounds__(256)
void flash(const bf16* __restrict__ Q, const bf16* __restrict__ K,
           const bf16* __restrict__ Vt, bf16* __restrict__ Y) {
    __shared__ __align__(16) bf16 ksh[2][8 * 512];   // 2 keyblk x 4 dstep
    __shared__ __align__(16) bf16 vsh[2][8 * 512];   // 2 dblk   x 4 kstep
    const int tid = threadIdx.x, lane = tid & 63, wave = tid >> 6;
    const int l32 = lane & 31, hi = lane >> 5;
    const int id = blockIdx.x;                       // 512 blocks
    const int bh = (id & 7) * 8 + ((id >> 3) & 7);   // XCD x -> heads 8x..8x+7
    const int qsb = id >> 6;                         // 0..7 (256-q superblock)
    const size_t kbase = (size_t)bh * T_SEQ * DH;    // Q,K: (B,H,T,D)
    const size_t vbase = (size_t)bh * DH * T_SEQ;    // Vt:  (B,H,D,T)
    const int q0 = qsb * 256 + wave * 32;            // tile A; tile B = q0+128

    // Q B-frags per tile: bq[tq][c][j] = Q[q0+tq*128+l32][c*16 + hi*8 + j]
    bf16x8 bq[2][4];
#pragma unroll
    for (int tq = 0; tq < 2; tq++) {
        const bf16* qp = Q + kbase + (size_t)(q0 + tq * 128 + l32) * DH + hi * 8;
#pragma unroll
        for (int c = 0; c < 4; c++) bq[tq][c] = *(const bf16x8*)(qp + c * 16);
    }

    f32x16 oT[2][2] = {};
    f32x16 lf[2] = {};       // li via MFMA: every elem = sum_k P[k][q]
    bf16x8 onesf;
#pragma unroll
    for (int j = 0; j < 8; j++) onesf[j] = (bf16)1.0f;

    // Stage 64 keys x 64 d of K and V(t) into buffer buf_.
#define STAGE(buf_, kt_) do {                                              \
        if (wave < 2) {                                                    \
            _Pragma("unroll")                                              \
            for (int u = 0; u < 4; u++) {                                  \
                const int s = wave * 4 + u, kb = s >> 2, c = s & 3;        \
                gld_lds16(K + kbase + (size_t)((kt_) + kb * 32 + l32) * DH \
                              + c * 16 + hi * 8,                           \
                          &ksh[buf_][s * 512]);                            \
            }                                                              \
        } else {                                                           \
            _Pragma("unroll")                                              \
            for (int u = 0; u < 4; u++) {                                  \
                const int s = (wave - 2) * 4 + u, db = s >> 2, kc = s & 3; \
                gld_lds16(Vt + vbase + (size_t)(db * 32 + l32) * T_SEQ     \
                              + (kt_) + kc * 16 + hi * 8,                  \
                          &vsh[buf_][s * 512]);                            \
            }                                                              \
        }                                                                  \
    } while (0)

    STAGE(0, 0);
    int ib = 0;
    for (int kt = 0; kt < T_SEQ; kt += 64, ib ^= 1) {
        __syncthreads();   // publishes buf ib; prior reads of ib^1 all done
        if (kt + 64 < T_SEQ) STAGE(ib ^ 1, kt + 64);

#pragma unroll
        for (int kb = 0; kb < 2; kb++) {
            // S^T for 32 keys x (2 x 32 q) — K-frag shared by both tiles
            f32x16 s0 = {}, s1 = {};
            __builtin_amdgcn_s_setprio(1);
#pragma unroll
            for (int c = 0; c < 4; c++) {
                const bf16x8 a = *(const bf16x8*)&ksh[ib][(kb * 4 + c) * 512 + lane * 8];
                s0 = MFMA32(a, bq[0][c], s0);
                s1 = MFMA32(a, bq[1][c], s1);
            }
            __builtin_amdgcn_s_setprio(0);
            // bare v_exp_f32 (log2e pre-folded) + bf16x2 pack, both tiles
            uint P[2][8];
#pragma unroll
            for (int w = 0; w < 8; w++) {
                P[0][w] = pack_bf16(fexp2(s0[2 * w]), fexp2(s0[2 * w + 1]));
                P[1][w] = pack_bf16(fexp2(s1[2 * w]), fexp2(s1[2 * w + 1]));
            }
            // PV per 16-key step; V-frags shared by both tiles.
            // swap(P0,P2): ret[0]={P0.lo,P2.lo}=u[0], ret[1]={P0.hi,P2.hi}=u[2]
#pragma unroll
            for (int t = 0; t < 2; t++) {
                const int kc = kb * 2 + t;
                bf16x8 vv[2];
#pragma unroll
                for (int db = 0; db < 2; db++)
                    vv[db] = *(const bf16x8*)&vsh[ib][(db * 4 + kc) * 512 + lane * 8];
#pragma unroll
                for (int tq = 0; tq < 2; tq++) {
                    const uintx2 rA = __builtin_amdgcn_permlane32_swap(
                        P[tq][4 * t + 0], P[tq][4 * t + 2], false, false);
                    const uintx2 rB = __builtin_amdgcn_permlane32_swap(
                        P[tq][4 * t + 1], P[tq][4 * t + 3], false, false);
                    union { uint u[4]; bf16x8 v; } bP;
                    bP.u[0] = rA[0]; bP.u[1] = rB[0];
                    bP.u[2] = rA[1]; bP.u[3] = rB[1];
                    __builtin_amdgcn_s_setprio(1);
                    lf[tq] = MFMA32(onesf, bP.v, lf[tq]);   // row-sum on MFMA pipe
#pragma unroll
                    for (int db = 0; db < 2; db++)
                        oT[tq][db] = MFMA32(vv[db], bP.v, oT[tq][db]);
                    __builtin_amdgcn_s_setprio(0);
                }
            }
        }
    }
#undef STAGE

    // O^T: d = db*32 + (reg&3) + 8*(reg>>2) + 4*hi, q = l32. Y is (B,T,C).
    const int b = bh >> 4, h = bh & 15;
#pragma unroll
    for (int tq = 0; tq < 2; tq++) {
        const float inv = 1.0f / lf[tq][0];
        const size_t yrow =
            ((size_t)b * T_SEQ + q0 + tq * 128 + l32) * CDIM + h * DH;
#pragma unroll
        for (int db = 0; db < 2; db++)
#pragma unroll
            for (int rg = 0; rg < 4; rg++) {
                bf16x4 o4 = { (bf16)(oT[tq][db][rg * 4 + 0] * inv),
                              (bf16)(oT[tq][db][rg * 4 + 1] * inv),
                              (bf16)(oT[tq][db][rg * 4 + 2] * inv),
                              (bf16)(oT[tq][db][rg * 4 + 3] * inv) };
                *(bf16x4*)(Y + yrow + db * 32 + 8 * rg + 4 * hi) = o4;
            }
    }
}

// ---------------------------------------------------------------------------
extern "C" void kernel_launch(void* const* d_in, const int* in_sizes, int n_in,
                              void* d_out, int out_size, void* d_ws, size_t ws_size,
                              hipStream_t stream) {
    const float* x      = (const float*)d_in[0];   // (4,2048,1024) fp32
    const float* w_attn = (const float*)d_in[1];   // (3072,1024) fp32
    const float* w_proj = (const float*)d_in[2];   // (1024,1024) fp32
    float* out = (float*)d_out;                    // (4,2048,1024) fp32

    bf16* ws = (bf16*)d_ws;
    const size_t SZ = (size_t)4 * NH * T_SEQ * DH;   // 8388608
    bf16* Xb  = ws;
    bf16* Wab = Xb + SZ;                             // 3145728
    bf16* Wpb = Wab + 3145728;                       // 1048576
    bf16* Qb  = Wpb + 1048576;
    bf16* Kb  = Qb + SZ;
    bf16* Vtb = Kb + SZ;                             // transposed (B,H,D,T)
    bf16* Yb  = Vtb + SZ;
    float2* tab = (float2*)(Yb + SZ);                // 2048*32 float2 = 512 KB

    rope_table<<<256, 256, 0, stream>>>(tab);
    cvt_f32_bf16<<<4096, 256, 0, stream>>>(x, Xb, 1048576);
    cvt_f32_bf16<<<1536, 256, 0, stream>>>(w_attn, Wab, 393216);
    cvt_f32_bf16<<<512, 256, 0, stream>>>(w_proj, Wpb, 131072);

    gemm_qkv<<<dim3(24, 64), 256, 0, stream>>>(Xb, Wab, Qb, Kb, Vtb, tab);
    flash<<<512, 256, 0, stream>>>(Qb, Kb, Vtb, Yb);
    gemm_proj<<<dim3(8, 64), 256, 0, stream>>>(Yb, Wpb, out);
}

// Round 12
// 318.551 us; speedup vs baseline: 1.0711x; 1.0711x over previous
//
#include <hip/hip_runtime.h>
#include <hip/hip_bf16.h>
#include <math.h>

typedef __bf16 bf16;
typedef float f32x4 __attribute__((ext_vector_type(4)));
typedef float f32x16 __attribute__((ext_vector_type(16)));
typedef bf16 bf16x8 __attribute__((ext_vector_type(8)));
typedef bf16 bf16x4 __attribute__((ext_vector_type(4)));
typedef unsigned int uint;
typedef uint uintx2 __attribute__((ext_vector_type(2)));

#define MFMA16(a, b, c) __builtin_amdgcn_mfma_f32_16x16x32_bf16(a, b, c, 0, 0, 0)
#define MFMA32(a, b, c) __builtin_amdgcn_mfma_f32_32x32x16_bf16(a, b, c, 0, 0, 0)

static constexpr int T_SEQ = 2048;
static constexpr int CDIM  = 1024;
static constexpr int NH    = 16;
static constexpr int DH    = 64;
static constexpr float FREQ_C = 0.20762050593045998f;   // log2(10000)/64
// 1/sqrt(64) * log2(e): folded into Q so flash uses bare exp2
static constexpr float Q_SCALE = 0.18033688011112042f;

// raw v_exp_f32 (1 trans op; no denormal-fixup expansion). Safe here: all
// results are normal-range, flush-to-zero unobservable after bf16 cast.
__device__ __forceinline__ float fexp2(float x) {
    return __builtin_amdgcn_exp2f(x);
}

// pack two f32 -> bf16x2 word via scalar casts; compiler fuses to the packed
// cvt with CORRECT operand order. (r11's hand-asm cvt_pk had a different
// packing convention -> pair scramble. Do not hand-write it.)
__device__ __forceinline__ uint pack_bf16(float lo, float hi) {
    union { bf16 h[2]; uint u; } cv;
    cv.h[0] = (bf16)lo;
    cv.h[1] = (bf16)hi;
    return cv.u;
}

// async global->LDS, 16B per lane. LDS dest is wave-uniform base + lane*16.
__device__ __forceinline__ void gld_lds16(const bf16* g, bf16* l) {
    __builtin_amdgcn_global_load_lds(
        (const __attribute__((address_space(1))) void*)g,
        (__attribute__((address_space(3))) void*)l, 16, 0, 0);
}

// Accurate fast sincos: 2-term Cody-Waite reduction to [-pi,pi], then native.
__device__ __forceinline__ void fast_sincos(float x, float* s, float* c) {
    const float INV2PI = 0.15915494309189535f;
    const float PI2_HI = 6.28125f;
    const float PI2_LO = 1.9353071795864769e-3f;
    const float n = rintf(x * INV2PI);
    float r = fmaf(-n, PI2_HI, x);
    r = fmaf(-n, PI2_LO, r);
    *s = __sinf(r);
    *c = __cosf(r);
}

__device__ __forceinline__ void cvt8(const float* __restrict__ in,
                                     bf16* __restrict__ out, int i) {
    const f32x4* p = (const f32x4*)(in + (size_t)i * 8);
    const f32x4 lo = p[0], hi = p[1];
    bf16x8 o;
    o[0] = (bf16)lo[0]; o[1] = (bf16)lo[1]; o[2] = (bf16)lo[2]; o[3] = (bf16)lo[3];
    o[4] = (bf16)hi[0]; o[5] = (bf16)hi[1]; o[6] = (bf16)hi[2]; o[7] = (bf16)hi[3];
    *(bf16x8*)(out + (size_t)i * 8) = o;
}

// ---------------------------------------------------------------------------
// Fused prologue: all 3 fp32->bf16 conversions + RoPE table in ONE launch
// (replaces 4 kernels -> saves 3 dispatch gaps + tail underutilization).
// Block ranges: [0,4096) x | [4096,5632) w_attn | [5632,6144) w_proj |
// [6144,6400) rope table. All ranges exact multiples of 256 threads.
// ---------------------------------------------------------------------------
__global__ __launch_bounds__(256)
void prologue(const float* __restrict__ x, const float* __restrict__ wa,
              const float* __restrict__ wp, bf16* __restrict__ Xb,
              bf16* __restrict__ Wab, bf16* __restrict__ Wpb,
              float2* __restrict__ tab) {
    const int b = blockIdx.x, tid = threadIdx.x;
    if (b < 4096) {
        cvt8(x, Xb, b * 256 + tid);
    } else if (b < 5632) {
        cvt8(wa, Wab, (b - 4096) * 256 + tid);
    } else if (b < 6144) {
        cvt8(wp, Wpb, (b - 5632) * 256 + tid);
    } else {
        const int i = (b - 6144) * 256 + tid;       // 2048*32 entries
        const int t = i >> 5, p = i & 31;
        const float ang = (float)t * exp2f(-2.0f * (float)p * FREQ_C);
        float s, c;
        fast_sincos(ang, &s, &c);
        tab[i] = make_float2(c, s);
    }
}

// ---------------------------------------------------------------------------
// 128x128 GEMM core, BK=64, 2-barrier (r12-proven). SIX schedule variants
// (2-bar / dbuf / reads-first / dual-M / counted-vmcnt / BK=128) all measured
// 117+-1us on qkv -> this 4-wave 128^2 structure is at its floor (440 TF,
// matching the documented m97-structure plateau). Escape requires the
// 512-thread 256^2 8-phase structure, not schedule tweaks here.
// ---------------------------------------------------------------------------
#define GEMM_CORE(Abase, Bbase, KDIM)                                            \
    f32x4 acc[4][4] = {};                                                        \
    for (int kk = 0; kk < (KDIM); kk += 64) {                                    \
        __syncthreads();                                                         \
        _Pragma("unroll")                                                        \
        for (int u = 0; u < 4; u++) {                                            \
            const int st = wave * 4 + u, mg = st >> 1, kg = st & 1;              \
            gld_lds16(Abase + (size_t)(mg * 16 + sm) * (KDIM) + kk + kg * 32 + sc * 8, \
                      &ash[st * 512]);                                           \
            gld_lds16(Bbase + (size_t)(mg * 16 + sm) * (KDIM) + kk + kg * 32 + sc * 8, \
                      &bsh[st * 512]);                                           \
        }                                                                        \
        __syncthreads();                                                         \
        _Pragma("unroll")                                                        \
        for (int kg = 0; kg < 2; kg++) {                                         \
            bf16x8 af[4], bfr[4];                                                \
            _Pragma("unroll")                                                    \
            for (int a = 0; a < 4; a++)                                          \
                af[a] = *(const bf16x8*)&ash[((wm * 4 + a) * 2 + kg) * 512 + lane * 8]; \
            _Pragma("unroll")                                                    \
            for (int b = 0; b < 4; b++)                                          \
                bfr[b] = *(const bf16x8*)&bsh[((wn * 4 + b) * 2 + kg) * 512 + lane * 8]; \
            _Pragma("unroll")                                                    \
            for (int a = 0; a < 4; a++)                                          \
                _Pragma("unroll")                                                \
                for (int b = 0; b < 4; b++)                                      \
                    acc[a][b] = MFMA16(af[a], bfr[b], acc[a][b]);                \
        }                                                                        \
    }

// ---------------------------------------------------------------------------
// QKV GEMM + fused RoPE (table-driven). Q,K -> (B,H,T,D); V -> (B,H,D,T).
// Q pre-scaled by 1/sqrt(64)*log2(e)  (flash uses exp2 directly).
// XCD-chunked swizzle, bm-fastest within chunk (r16-verified FETCH 85->51MB,
// per-XCD resident set 8 X-panels + 8 W-panels = 4MB = L2). 1536 % 8 == 0.
// ---------------------------------------------------------------------------
__global__ __launch_bounds__(256)
void gemm_qkv(const bf16* __restrict__ X, const bf16* __restrict__ W,
              bf16* __restrict__ Qo, bf16* __restrict__ Ko, bf16* __restrict__ Vt,
              const float2* __restrict__ tab) {
    __shared__ __align__(16) bf16 ash[16 * 512];
    __shared__ __align__(16) bf16 bsh[16 * 512];
    const int tid = threadIdx.x, lane = tid & 63, wave = tid >> 6;
    const int quad = lane >> 4, l16 = lane & 15;
    const int wm = wave >> 1, wn = wave & 1;
    const int lin = blockIdx.y * 24 + blockIdx.x;        // 0..1535
    const int xcd = lin & 7, j = lin >> 3;               // j in [0,192)
    const int bm = xcd * 8 + (j & 7), bn = j >> 3;       // bm-fastest in chunk
    const int sm = lane & 15, sc = lane >> 4;

    const bf16* Abase = X + (size_t)(bm * 128) * CDIM;
    const bf16* Bbase = W + (size_t)(bn * 128) * CDIM;
    GEMM_CORE(Abase, Bbase, CDIM)

    const int rr    = (bn * 128) >> 10;          // 0=q 1=k 2=v (block-uniform)
    const int nsec  = (bn * 128) & 1023;
    const int batch = (bm * 128) >> 11;
    const int tb    = ((bm * 128) & 2047) + wm * 64;

    if (rr == 2) {
#pragma unroll
        for (int b = 0; b < 4; b++) {
            const int n = nsec + wn * 64 + b * 16 + l16;
            const int h = n >> 6, d = n & 63;
            bf16* vp = Vt + ((size_t)(batch * NH + h) * DH + d) * T_SEQ;
#pragma unroll
            for (int a = 0; a < 4; a++) {
                const int t0 = tb + a * 16 + quad * 4;
                bf16x4 pk4 = { (bf16)acc[a][b][0], (bf16)acc[a][b][1],
                               (bf16)acc[a][b][2], (bf16)acc[a][b][3] };
                *(bf16x4*)(vp + t0) = pk4;
            }
        }
    } else {
        bf16* Dst = (rr == 0) ? Qo : Ko;
        const float scale = (rr == 0) ? Q_SCALE : 1.0f;
#pragma unroll
        for (int b = 0; b < 4; b++) {
            const int n = nsec + wn * 64 + b * 16 + l16;
            const int h = n >> 6, d = n & 63;
            const int p = d >> 1, odd = d & 1;
            bf16* dp = Dst + (size_t)(batch * NH + h) * T_SEQ * DH + d;
#pragma unroll
            for (int a = 0; a < 4; a++) {
#pragma unroll
                for (int r = 0; r < 4; r++) {
                    const int t = tb + a * 16 + quad * 4 + r;
                    const float val = acc[a][b][r];
                    const float partner = __shfl_xor(val, 1);  // pair element d^1
                    const float2 cs = tab[t * 32 + p];
                    float o = odd ? (partner * cs.y + val * cs.x)
                                  : (val * cs.x - partner * cs.y);
                    dp[(size_t)t * DH] = (bf16)(o * scale);
                }
            }
        }
    }
}

// ---------------------------------------------------------------------------
// Out-projection GEMM, fp32 output. Same core + chunked swizzle, bm-fastest
// (512 % 8 == 0).
// ---------------------------------------------------------------------------
__global__ __launch_bounds__(256)
void gemm_proj(const bf16* __restrict__ X, const bf16* __restrict__ W,
               float* __restrict__ Out) {
    __shared__ __align__(16) bf16 ash[16 * 512];
    __shared__ __align__(16) bf16 bsh[16 * 512];
    const int tid = threadIdx.x, lane = tid & 63, wave = tid >> 6;
    const int quad = lane >> 4, l16 = lane & 15;
    const int wm = wave >> 1, wn = wave & 1;
    const int lin = blockIdx.y * 8 + blockIdx.x;         // 0..511
    const int xcd = lin & 7, j = lin >> 3;               // j in [0,64)
    const int bm = xcd * 8 + (j & 7), bn = j >> 3;       // bm-fastest in chunk
    const int sm = lane & 15, sc = lane >> 4;

    const bf16* Abase = X + (size_t)(bm * 128) * CDIM;
    const bf16* Bbase = W + (size_t)(bn * 128) * CDIM;
    GEMM_CORE(Abase, Bbase, CDIM)

#pragma unroll
    for (int b = 0; b < 4; b++) {
        const int n = bn * 128 + wn * 64 + b * 16 + l16;
#pragma unroll
        for (int a = 0; a < 4; a++) {
            const int m = bm * 128 + wm * 64 + a * 16 + quad * 4;
#pragma unroll
            for (int r = 0; r < 4; r++)
                Out[(size_t)(m + r) * CDIM + n] = acc[a][b][r];
        }
    }
}

// ---------------------------------------------------------------------------
// Flash r13 EXACT (the 322.8us-verified config; r11's setprio variant cost
// ~10us — flash's 4 waves are barrier-lockstep per tile = m190's null/negative
// setprio regime, not m191's independent-block regime): 2 q-tiles per wave
// (256 q rows/block, grid 512), shared K/V LDS reads, single-barrier
// double-buffered staging, bare v_exp_f32, permlane32_swap P^T assembly,
// row-sum li on the MFMA pipe.
// permlane32_swap convention (r10-verified):
//   ret[0] (vdst') = {vdst.lo , src0.lo}; ret[1] (src0') = {vdst.hi , src0.hi}
// ---------------------------------------------------------------------------
__global__ __launch_bounds__(256)
void flash(const bf16* __restrict__ Q, const bf16* __restrict__ K,
           const bf16* __restrict__ Vt, bf16* __restrict__ Y) {
    __shared__ __align__(16) bf16 ksh[2][8 * 512];   // 2 keyblk x 4 dstep
    __shared__ __align__(16) bf16 vsh[2][8 * 512];   // 2 dblk   x 4 kstep
    const int tid = threadIdx.x, lane = tid & 63, wave = tid >> 6;
    const int l32 = lane & 31, hi = lane >> 5;
    const int id = blockIdx.x;                       // 512 blocks
    const int bh = (id & 7) * 8 + ((id >> 3) & 7);   // XCD x -> heads 8x..8x+7
    const int qsb = id >> 6;                         // 0..7 (256-q superblock)
    const size_t kbase = (size_t)bh * T_SEQ * DH;    // Q,K: (B,H,T,D)
    const size_t vbase = (size_t)bh * DH * T_SEQ;    // Vt:  (B,H,D,T)
    const int q0 = qsb * 256 + wave * 32;            // tile A; tile B = q0+128

    // Q B-frags per tile: bq[tq][c][j] = Q[q0+tq*128+l32][c*16 + hi*8 + j]
    bf16x8 bq[2][4];
#pragma unroll
    for (int tq = 0; tq < 2; tq++) {
        const bf16* qp = Q + kbase + (size_t)(q0 + tq * 128 + l32) * DH + hi * 8;
#pragma unroll
        for (int c = 0; c < 4; c++) bq[tq][c] = *(const bf16x8*)(qp + c * 16);
    }

    f32x16 oT[2][2] = {};
    f32x16 lf[2] = {};       // li via MFMA: every elem = sum_k P[k][q]
    bf16x8 onesf;
#pragma unroll
    for (int j = 0; j < 8; j++) onesf[j] = (bf16)1.0f;

    // Stage 64 keys x 64 d of K and V(t) into buffer buf_.
#define STAGE(buf_, kt_) do {                                              \
        if (wave < 2) {                                                    \
            _Pragma("unroll")                                              \
            for (int u = 0; u < 4; u++) {                                  \
                const int s = wave * 4 + u, kb = s >> 2, c = s & 3;        \
                gld_lds16(K + kbase + (size_t)((kt_) + kb * 32 + l32) * DH \
                              + c * 16 + hi * 8,                           \
                          &ksh[buf_][s * 512]);                            \
            }                                                              \
        } else {                                                           \
            _Pragma("unroll")                                              \
            for (int u = 0; u < 4; u++) {                                  \
                const int s = (wave - 2) * 4 + u, db = s >> 2, kc = s & 3; \
                gld_lds16(Vt + vbase + (size_t)(db * 32 + l32) * T_SEQ     \
                              + (kt_) + kc * 16 + hi * 8,                  \
                          &vsh[buf_][s * 512]);                            \
            }                                                              \
        }                                                                  \
    } while (0)

    STAGE(0, 0);
    int ib = 0;
    for (int kt = 0; kt < T_SEQ; kt += 64, ib ^= 1) {
        __syncthreads();   // publishes buf ib; prior reads of ib^1 all done
        if (kt + 64 < T_SEQ) STAGE(ib ^ 1, kt + 64);

#pragma unroll
        for (int kb = 0; kb < 2; kb++) {
            // S^T for 32 keys x (2 x 32 q) — K-frag shared by both tiles
            f32x16 s0 = {}, s1 = {};
#pragma unroll
            for (int c = 0; c < 4; c++) {
                const bf16x8 a = *(const bf16x8*)&ksh[ib][(kb * 4 + c) * 512 + lane * 8];
                s0 = MFMA32(a, bq[0][c], s0);
                s1 = MFMA32(a, bq[1][c], s1);
            }
            // bare v_exp_f32 (log2e pre-folded) + bf16x2 pack, both tiles
            uint P[2][8];
#pragma unroll
            for (int w = 0; w < 8; w++) {
                P[0][w] = pack_bf16(fexp2(s0[2 * w]), fexp2(s0[2 * w + 1]));
                P[1][w] = pack_bf16(fexp2(s1[2 * w]), fexp2(s1[2 * w + 1]));
            }
            // PV per 16-key step; V-frags shared by both tiles.
            // swap(P0,P2): ret[0]={P0.lo,P2.lo}=u[0], ret[1]={P0.hi,P2.hi}=u[2]
#pragma unroll
            for (int t = 0; t < 2; t++) {
                const int kc = kb * 2 + t;
                bf16x8 vv[2];
#pragma unroll
                for (int db = 0; db < 2; db++)
                    vv[db] = *(const bf16x8*)&vsh[ib][(db * 4 + kc) * 512 + lane * 8];
#pragma unroll
                for (int tq = 0; tq < 2; tq++) {
                    const uintx2 rA = __builtin_amdgcn_permlane32_swap(
                        P[tq][4 * t + 0], P[tq][4 * t + 2], false, false);
                    const uintx2 rB = __builtin_amdgcn_permlane32_swap(
                        P[tq][4 * t + 1], P[tq][4 * t + 3], false, false);
                    union { uint u[4]; bf16x8 v; } bP;
                    bP.u[0] = rA[0]; bP.u[1] = rB[0];
                    bP.u[2] = rA[1]; bP.u[3] = rB[1];
                    lf[tq] = MFMA32(onesf, bP.v, lf[tq]);   // row-sum on MFMA pipe
#pragma unroll
                    for (int db = 0; db < 2; db++)
                        oT[tq][db] = MFMA32(vv[db], bP.v, oT[tq][db]);
                }
            }
        }
    }
#undef STAGE

    // O^T: d = db*32 + (reg&3) + 8*(reg>>2) + 4*hi, q = l32. Y is (B,T,C).
    const int b = bh >> 4, h = bh & 15;
#pragma unroll
    for (int tq = 0; tq < 2; tq++) {
        const float inv = 1.0f / lf[tq][0];
        const size_t yrow =
            ((size_t)b * T_SEQ + q0 + tq * 128 + l32) * CDIM + h * DH;
#pragma unroll
        for (int db = 0; db < 2; db++)
#pragma unroll
            for (int rg = 0; rg < 4; rg++) {
                bf16x4 o4 = { (bf16)(oT[tq][db][rg * 4 + 0] * inv),
                              (bf16)(oT[tq][db][rg * 4 + 1] * inv),
                              (bf16)(oT[tq][db][rg * 4 + 2] * inv),
                              (bf16)(oT[tq][db][rg * 4 + 3] * inv) };
                *(bf16x4*)(Y + yrow + db * 32 + 8 * rg + 4 * hi) = o4;
            }
    }
}

// ---------------------------------------------------------------------------
extern "C" void kernel_launch(void* const* d_in, const int* in_sizes, int n_in,
                              void* d_out, int out_size, void* d_ws, size_t ws_size,
                              hipStream_t stream) {
    const float* x      = (const float*)d_in[0];   // (4,2048,1024) fp32
    const float* w_attn = (const float*)d_in[1];   // (3072,1024) fp32
    const float* w_proj = (const float*)d_in[2];   // (1024,1024) fp32
    float* out = (float*)d_out;                    // (4,2048,1024) fp32

    bf16* ws = (bf16*)d_ws;
    const size_t SZ = (size_t)4 * NH * T_SEQ * DH;   // 8388608
    bf16* Xb  = ws;
    bf16* Wab = Xb + SZ;                             // 3145728
    bf16* Wpb = Wab + 3145728;                       // 1048576
    bf16* Qb  = Wpb + 1048576;
    bf16* Kb  = Qb + SZ;
    bf16* Vtb = Kb + SZ;                             // transposed (B,H,D,T)
    bf16* Yb  = Vtb + SZ;
    float2* tab = (float2*)(Yb + SZ);                // 2048*32 float2 = 512 KB

    prologue<<<6400, 256, 0, stream>>>(x, w_attn, w_proj, Xb, Wab, Wpb, tab);
    gemm_qkv<<<dim3(24, 64), 256, 0, stream>>>(Xb, Wab, Qb, Kb, Vtb, tab);
    flash<<<512, 256, 0, stream>>>(Qb, Kb, Vtb, Yb);
    gemm_proj<<<dim3(8, 64), 256, 0, stream>>>(Yb, Wpb, out);
}